// Round 1
// baseline (901.475 us; speedup 1.0000x reference)
//
#include <hip/hip_runtime.h>
#include <math.h>

#define F1 128
#define C2N 8
#define SLOPE 0.2f
#define EPSBN 1e-5f

__device__ __forceinline__ unsigned fenc(float f){
  unsigned u = __float_as_uint(f);
  return (u & 0x80000000u) ? ~u : (u | 0x80000000u);
}
__device__ __forceinline__ float fdec(unsigned u){
  return (u & 0x80000000u) ? __uint_as_float(u & 0x7FFFFFFFu) : __uint_as_float(~u);
}

// ---- BatchNorm stats: thread = feature, block strides rows ----
__global__ __launch_bounds__(128) void k_bn_stats(const float* __restrict__ x,
    float* __restrict__ sum, float* __restrict__ sumsq, int n){
  int f = threadIdx.x;
  float s = 0.f, ss = 0.f;
  for (int r = blockIdx.x; r < n; r += gridDim.x){
    float v = x[(size_t)r*F1 + f];
    s += v; ss += v*v;
  }
  atomicAdd(&sum[f], s);
  atomicAdd(&sumsq[f], ss);
}

__global__ __launch_bounds__(128) void k_bn_final(const float* __restrict__ sum,
    const float* __restrict__ sumsq, const float* __restrict__ gamma,
    const float* __restrict__ beta, float* __restrict__ ab, int n){
  int f = threadIdx.x;
  float inv_n = 1.f / (float)n;
  float mean = sum[f] * inv_n;
  float var  = sumsq[f] * inv_n - mean*mean;
  float inv  = rsqrtf(var + EPSBN);
  float a = inv * gamma[f];
  ab[f]      = a;
  ab[F1 + f] = beta[f] - mean*a;
}

// ---- normalize + x@W1 (128x128) + al1/ar1 head reductions ----
__global__ __launch_bounds__(128) void k_gemm1(const float* __restrict__ x,
    const float* __restrict__ ab, const float* __restrict__ W1,
    const float* __restrict__ asrc, const float* __restrict__ adst,
    float* __restrict__ h1, float* __restrict__ al, float* __restrict__ ar, int n){
  const int j  = threadIdx.x;
  const int r0 = blockIdx.x * 8;
  __shared__ float xs[8][F1];
  float A = ab[j], B = ab[F1 + j];
  int nr = n - r0; if (nr > 8) nr = 8;
  for (int rr = 0; rr < nr; ++rr)
    xs[rr][j] = x[(size_t)(r0+rr)*F1 + j] * A + B;
  __syncthreads();
  float acc[8] = {0,0,0,0,0,0,0,0};
  for (int k = 0; k < F1; ++k){
    float w = W1[k*F1 + j];
    #pragma unroll
    for (int rr = 0; rr < 8; ++rr) acc[rr] += xs[rr][k] * w;
  }
  float as = asrc[j], ad = adst[j];
  for (int rr = 0; rr < nr; ++rr){
    float hv = acc[rr];
    h1[(size_t)(r0+rr)*F1 + j] = hv;
    float vs = hv*as, vd = hv*ad;
    #pragma unroll
    for (int mk = 1; mk < 32; mk <<= 1){
      vs += __shfl_xor(vs, mk);
      vd += __shfl_xor(vd, mk);
    }
    if ((j & 31) == 0){
      al[(r0+rr)*4 + (j>>5)] = vs;
      ar[(r0+rr)*4 + (j>>5)] = vd;
    }
  }
}

// ---- layer-1 edge pass A: per-dst segment max (ordered-uint atomicMax) ----
__global__ __launch_bounds__(256) void k_edge_max1(const int* __restrict__ ei,
    const float* __restrict__ al, const float* __restrict__ ar,
    unsigned* __restrict__ m, int E, int Etot){
  int e = blockIdx.x*blockDim.x + threadIdx.x;
  if (e >= Etot) return;
  int s = (e < E) ? ei[e]     : (e - E);
  int d = (e < E) ? ei[E + e] : (e - E);
  #pragma unroll
  for (int h = 0; h < 4; ++h){
    float v = al[s*4+h] + ar[d*4+h];
    v = v > 0.f ? v : SLOPE*v;
    atomicMax(&m[d*4+h], fenc(v));
  }
}

// ---- layer-1 edge pass B: scatter exp-weighted features + denominators ----
__global__ __launch_bounds__(256) void k_edge_acc1(const int* __restrict__ ei,
    const float* __restrict__ al, const float* __restrict__ ar,
    const unsigned* __restrict__ m, const float* __restrict__ h1,
    float* __restrict__ denom, float* __restrict__ acc, int E, int Etot){
  int eg = blockIdx.x*2 + (threadIdx.x >> 7);
  if (eg >= Etot) return;
  int f = threadIdx.x & 127;
  int s = (eg < E) ? ei[eg]     : (eg - E);
  int d = (eg < E) ? ei[E + eg] : (eg - E);
  int h = f >> 5;
  float v = al[s*4+h] + ar[d*4+h];
  v = v > 0.f ? v : SLOPE*v;
  float ex = expf(v - fdec(m[d*4+h]));
  if ((f & 31) == 0) atomicAdd(&denom[d*4+h], ex);
  atomicAdd(&acc[(size_t)d*F1 + f], ex * h1[(size_t)s*F1 + f]);
}

// ---- finalize layer 1: x1 = ELU(acc/denom + b1) ----
__global__ __launch_bounds__(256) void k_fin1(const float* __restrict__ acc,
    const float* __restrict__ denom, const float* __restrict__ b1,
    float* __restrict__ x1, int n){
  int idx = blockIdx.x*blockDim.x + threadIdx.x;
  if (idx >= n*F1) return;
  int r = idx >> 7, f = idx & 127;
  float v = acc[idx] / (denom[r*4 + (f>>5)] + 1e-16f) + b1[f];
  x1[idx] = v > 0.f ? v : expm1f(v);
}

// ---- x1@W2 (128x8) + al2/ar2 ----
__global__ __launch_bounds__(256) void k_gemm2(const float* __restrict__ x1,
    const float* __restrict__ W2, const float* __restrict__ as2,
    const float* __restrict__ ad2, float* __restrict__ h2,
    float* __restrict__ al2, float* __restrict__ ar2, int n){
  int r = blockIdx.x*32 + (threadIdx.x >> 3);
  int j = threadIdx.x & 7;
  if (r >= n) return;
  const float* xr = x1 + (size_t)r*F1;
  float a = 0.f;
  for (int k = 0; k < F1; ++k) a += xr[k] * W2[k*C2N + j];
  h2[(size_t)r*C2N + j] = a;
  float vs = a*as2[j], vd = a*ad2[j];
  #pragma unroll
  for (int mk = 1; mk < 8; mk <<= 1){
    vs += __shfl_xor(vs, mk);
    vd += __shfl_xor(vd, mk);
  }
  if (j == 0){ al2[r] = vs; ar2[r] = vd; }
}

// ---- layer-2 edge pass A ----
__global__ __launch_bounds__(256) void k_edge_max2(const int* __restrict__ ei,
    const float* __restrict__ al, const float* __restrict__ ar,
    unsigned* __restrict__ m, int E, int Etot){
  int e = blockIdx.x*blockDim.x + threadIdx.x;
  if (e >= Etot) return;
  int s = (e < E) ? ei[e]     : (e - E);
  int d = (e < E) ? ei[E + e] : (e - E);
  float v = al[s] + ar[d];
  v = v > 0.f ? v : SLOPE*v;
  atomicMax(&m[d], fenc(v));
}

// ---- layer-2 edge pass B ----
__global__ __launch_bounds__(256) void k_edge_acc2(const int* __restrict__ ei,
    const float* __restrict__ al, const float* __restrict__ ar,
    const unsigned* __restrict__ m, const float* __restrict__ h2,
    float* __restrict__ denom, float* __restrict__ acc, int E, int Etot){
  int eg = blockIdx.x*32 + (threadIdx.x >> 3);
  if (eg >= Etot) return;
  int j = threadIdx.x & 7;
  int s = (eg < E) ? ei[eg]     : (eg - E);
  int d = (eg < E) ? ei[E + eg] : (eg - E);
  float v = al[s] + ar[d];
  v = v > 0.f ? v : SLOPE*v;
  float ex = expf(v - fdec(m[d]));
  if (j == 0) atomicAdd(&denom[d], ex);
  atomicAdd(&acc[(size_t)d*C2N + j], ex * h2[(size_t)s*C2N + j]);
}

// ---- finalize layer 2 + pool scatter ----
__global__ __launch_bounds__(256) void k_pool(const float* __restrict__ acc2,
    const float* __restrict__ denom2, const float* __restrict__ b2,
    const int* __restrict__ batch, float* __restrict__ pooled,
    float* __restrict__ cnt, int n){
  int r = blockIdx.x*32 + (threadIdx.x >> 3);
  int j = threadIdx.x & 7;
  if (r >= n) return;
  float v = acc2[(size_t)r*C2N + j] / (denom2[r] + 1e-16f) + b2[j];
  int g = batch[r];
  atomicAdd(&pooled[g*C2N + j], v);
  if (j == 0) atomicAdd(&cnt[g], 1.f);
}

// ---- mean + log_softmax ----
__global__ __launch_bounds__(256) void k_final(const float* __restrict__ pooled,
    const float* __restrict__ cnt, float* __restrict__ out, int G){
  int g = blockIdx.x*blockDim.x + threadIdx.x;
  if (g >= G) return;
  float c = cnt[g]; c = c > 1.f ? c : 1.f;
  float p[8]; float mx = -1e30f;
  #pragma unroll
  for (int j = 0; j < 8; ++j){ p[j] = pooled[g*8+j] / c; mx = fmaxf(mx, p[j]); }
  float s = 0.f;
  #pragma unroll
  for (int j = 0; j < 8; ++j) s += expf(p[j]-mx);
  float lse = mx + logf(s);
  #pragma unroll
  for (int j = 0; j < 8; ++j) out[g*8+j] = p[j] - lse;
}

extern "C" void kernel_launch(void* const* d_in, const int* in_sizes, int n_in,
                              void* d_out, int out_size, void* d_ws, size_t ws_size,
                              hipStream_t stream){
  const float* x    = (const float*)d_in[0];
  const float* gam  = (const float*)d_in[1];
  const float* bet  = (const float*)d_in[2];
  const float* W1   = (const float*)d_in[3];
  const float* as1  = (const float*)d_in[4];
  const float* ad1  = (const float*)d_in[5];
  const float* b1   = (const float*)d_in[6];
  const float* W2   = (const float*)d_in[7];
  const float* as2  = (const float*)d_in[8];
  const float* ad2  = (const float*)d_in[9];
  const float* b2   = (const float*)d_in[10];
  const int*   ei   = (const int*)d_in[11];
  const int*   batch= (const int*)d_in[12];

  int N = in_sizes[0] / F1;
  int E = in_sizes[11] / 2;
  int G = out_size / C2N;
  int Etot = E + N;

  float* ws = (float*)d_ws;
  // ---- zero-init region (single memset; ordered-uint max treats 0 as -inf) ----
  float*    sum    = ws;                                  // 128
  float*    sumsq  = sum + 128;                           // 128
  unsigned* m1     = (unsigned*)(sumsq + 128);            // N*4
  float*    denom1 = (float*)(m1 + (size_t)N*4);          // N*4
  float*    acc1   = denom1 + (size_t)N*4;                // N*128
  unsigned* m2     = (unsigned*)(acc1 + (size_t)N*F1);    // N
  float*    denom2 = (float*)(m2 + N);                    // N
  float*    acc2   = denom2 + N;                          // N*8
  float*    pooled = acc2 + (size_t)N*C2N;                // G*8
  float*    cnt    = pooled + (size_t)G*C2N;              // G
  float*    zend   = cnt + G;
  size_t zero_bytes = (size_t)((char*)zend - (char*)ws);
  // ---- non-zeroed region ----
  float* ab  = zend;                                      // 256
  float* h1  = ab + 256;                                  // N*128 (x1 aliases this)
  float* al1 = h1 + (size_t)N*F1;                         // N*4
  float* ar1 = al1 + (size_t)N*4;                         // N*4
  float* h2  = ar1 + (size_t)N*4;                         // N*8
  float* al2 = h2 + (size_t)N*C2N;                        // N
  float* ar2 = al2 + N;                                   // N

  hipMemsetAsync(d_ws, 0, zero_bytes, stream);

  k_bn_stats<<<512, 128, 0, stream>>>(x, sum, sumsq, N);
  k_bn_final<<<1, 128, 0, stream>>>(sum, sumsq, gam, bet, ab, N);
  k_gemm1<<<(N + 7)/8, 128, 0, stream>>>(x, ab, W1, as1, ad1, h1, al1, ar1, N);
  k_edge_max1<<<(Etot + 255)/256, 256, 0, stream>>>(ei, al1, ar1, m1, E, Etot);
  k_edge_acc1<<<(Etot + 1)/2, 256, 0, stream>>>(ei, al1, ar1, m1, h1, denom1, acc1, E, Etot);
  k_fin1<<<((N*F1) + 255)/256, 256, 0, stream>>>(acc1, denom1, b1, h1, N);
  k_gemm2<<<(N + 31)/32, 256, 0, stream>>>(h1, W2, as2, ad2, h2, al2, ar2, N);
  k_edge_max2<<<(Etot + 255)/256, 256, 0, stream>>>(ei, al2, ar2, m2, E, Etot);
  k_edge_acc2<<<(Etot + 31)/32, 256, 0, stream>>>(ei, al2, ar2, m2, h2, denom2, acc2, E, Etot);
  k_pool<<<(N + 31)/32, 256, 0, stream>>>(acc2, denom2, b2, batch, pooled, cnt, N);
  k_final<<<(G + 255)/256, 256, 0, stream>>>(pooled, cnt, (float*)d_out, G);
}

// Round 2
// 515.745 us; speedup vs baseline: 1.7479x; 1.7479x over previous
//
#include <hip/hip_runtime.h>
#include <math.h>

#define F1 128
#define C2N 8
#define SLOPE 0.2f
#define EPSBN 1e-5f

// ---- BatchNorm stats: thread = feature, block strides rows ----
__global__ __launch_bounds__(128) void k_bn_stats(const float* __restrict__ x,
    float* __restrict__ sum, float* __restrict__ sumsq, int n){
  int f = threadIdx.x;
  float s = 0.f, ss = 0.f;
  for (int r = blockIdx.x; r < n; r += gridDim.x){
    float v = x[(size_t)r*F1 + f];
    s += v; ss += v*v;
  }
  atomicAdd(&sum[f], s);
  atomicAdd(&sumsq[f], ss);
}

__global__ __launch_bounds__(128) void k_bn_final(const float* __restrict__ sum,
    const float* __restrict__ sumsq, const float* __restrict__ gamma,
    const float* __restrict__ beta, float* __restrict__ ab, int n){
  int f = threadIdx.x;
  float inv_n = 1.f / (float)n;
  float mean = sum[f] * inv_n;
  float var  = sumsq[f] * inv_n - mean*mean;
  float inv  = rsqrtf(var + EPSBN);
  float a = inv * gamma[f];
  ab[f]      = a;
  ab[F1 + f] = beta[f] - mean*a;
}

// ---- normalize + x@W1 (128x128) + al1/ar1 head reductions ----
__global__ __launch_bounds__(128) void k_gemm1(const float* __restrict__ x,
    const float* __restrict__ ab, const float* __restrict__ W1,
    const float* __restrict__ asrc, const float* __restrict__ adst,
    float* __restrict__ h1, float* __restrict__ al, float* __restrict__ ar, int n){
  const int j  = threadIdx.x;
  const int r0 = blockIdx.x * 8;
  __shared__ float xs[8][F1];
  float A = ab[j], B = ab[F1 + j];
  int nr = n - r0; if (nr > 8) nr = 8;
  for (int rr = 0; rr < nr; ++rr)
    xs[rr][j] = x[(size_t)(r0+rr)*F1 + j] * A + B;
  __syncthreads();
  float acc[8] = {0,0,0,0,0,0,0,0};
  for (int k = 0; k < F1; ++k){
    float w = W1[k*F1 + j];
    #pragma unroll
    for (int rr = 0; rr < 8; ++rr) acc[rr] += xs[rr][k] * w;
  }
  float as = asrc[j], ad = adst[j];
  for (int rr = 0; rr < nr; ++rr){
    float hv = acc[rr];
    h1[(size_t)(r0+rr)*F1 + j] = hv;
    float vs = hv*as, vd = hv*ad;
    #pragma unroll
    for (int mk = 1; mk < 32; mk <<= 1){
      vs += __shfl_xor(vs, mk);
      vd += __shfl_xor(vd, mk);
    }
    if ((j & 31) == 0){
      al[(r0+rr)*4 + (j>>5)] = vs;
      ar[(r0+rr)*4 + (j>>5)] = vd;
    }
  }
}

// ---- CSR build: dst-degree histogram ----
__global__ __launch_bounds__(256) void k_deg(const int* __restrict__ ei,
    int* __restrict__ deg, int E, int Etot){
  int e = blockIdx.x*blockDim.x + threadIdx.x;
  if (e >= Etot) return;
  int d = (e < E) ? ei[E + e] : (e - E);
  atomicAdd(&deg[d], 1);
}

// ---- exclusive scan over N degrees (single block) ----
__global__ __launch_bounds__(1024) void k_scan(const int* __restrict__ deg,
    int* __restrict__ rowptr, int* __restrict__ cursor, int n, int Etot){
  __shared__ int ls[1024];
  int t = threadIdx.x;
  int C = (n + 1023) / 1024;
  int b = t*C, e = b+C; if (e > n) e = n;
  int s = 0;
  for (int i = b; i < e; ++i) s += deg[i];
  ls[t] = s; __syncthreads();
  for (int off = 1; off < 1024; off <<= 1){
    int v = (t >= off) ? ls[t-off] : 0;
    __syncthreads();
    ls[t] += v;
    __syncthreads();
  }
  int run = (t == 0) ? 0 : ls[t-1];
  for (int i = b; i < e; ++i){
    rowptr[i] = run; cursor[i] = run; run += deg[i];
  }
  if (t == 1023) rowptr[n] = Etot;
}

// ---- CSR fill: scatter src into dst-sorted order ----
__global__ __launch_bounds__(256) void k_fill(const int* __restrict__ ei,
    int* __restrict__ cursor, int* __restrict__ csr_src, int E, int Etot){
  int e = blockIdx.x*blockDim.x + threadIdx.x;
  if (e >= Etot) return;
  int s = (e < E) ? ei[e]     : (e - E);
  int d = (e < E) ? ei[E + e] : (e - E);
  int pos = atomicAdd(&cursor[d], 1);
  csr_src[pos] = s;
}

// ---- layer-1 GAT gather: one 64-lane wave per node, 2 features/lane ----
__global__ __launch_bounds__(256) void k_gat1(const int* __restrict__ rowptr,
    const int* __restrict__ csr_src, const float* __restrict__ al,
    const float* __restrict__ ar, const float* __restrict__ h1,
    const float* __restrict__ b1, float* __restrict__ x1, int n){
  int node = blockIdx.x*4 + (threadIdx.x >> 6);
  if (node >= n) return;
  int lane = threadIdx.x & 63;
  int f0 = lane*2;
  int h  = f0 >> 5;
  int beg = rowptr[node], end = rowptr[node+1];
  float ard = ar[node*4 + h];
  // sweep 1: per-head max over incoming edges
  float mx = -1e30f;
  for (int e = beg; e < end; ++e){
    int s = csr_src[e];
    float v = al[s*4 + h] + ard;
    v = v > 0.f ? v : SLOPE*v;
    mx = fmaxf(mx, v);
  }
  // sweep 2: exp-weighted accumulate + denom, all in registers
  float a0 = 0.f, a1 = 0.f, den = 0.f;
  for (int e = beg; e < end; ++e){
    int s = csr_src[e];
    float v = al[s*4 + h] + ard;
    v = v > 0.f ? v : SLOPE*v;
    float ex = expf(v - mx);
    den += ex;
    float2 hv = *(const float2*)&h1[(size_t)s*F1 + f0];
    a0 += ex*hv.x; a1 += ex*hv.y;
  }
  float inv = 1.f / (den + 1e-16f);
  float v0 = a0*inv + b1[f0];
  float v1 = a1*inv + b1[f0+1];
  x1[(size_t)node*F1 + f0]   = v0 > 0.f ? v0 : expm1f(v0);
  x1[(size_t)node*F1 + f0+1] = v1 > 0.f ? v1 : expm1f(v1);
}

// ---- x1@W2 (128x8) + al2/ar2 ----
__global__ __launch_bounds__(256) void k_gemm2(const float* __restrict__ x1,
    const float* __restrict__ W2, const float* __restrict__ as2,
    const float* __restrict__ ad2, float* __restrict__ h2,
    float* __restrict__ al2, float* __restrict__ ar2, int n){
  int r = blockIdx.x*32 + (threadIdx.x >> 3);
  int j = threadIdx.x & 7;
  if (r >= n) return;
  const float* xr = x1 + (size_t)r*F1;
  float a = 0.f;
  for (int k = 0; k < F1; ++k) a += xr[k] * W2[k*C2N + j];
  h2[(size_t)r*C2N + j] = a;
  float vs = a*as2[j], vd = a*ad2[j];
  #pragma unroll
  for (int mk = 1; mk < 8; mk <<= 1){
    vs += __shfl_xor(vs, mk);
    vd += __shfl_xor(vd, mk);
  }
  if (j == 0){ al2[r] = vs; ar2[r] = vd; }
}

// ---- layer-2 GAT gather + bias + pool scatter: 8 lanes per node ----
__global__ __launch_bounds__(256) void k_gat2(const int* __restrict__ rowptr,
    const int* __restrict__ csr_src, const float* __restrict__ al,
    const float* __restrict__ ar, const float* __restrict__ h2,
    const float* __restrict__ b2, const int* __restrict__ batch,
    float* __restrict__ pooled, float* __restrict__ cnt, int n){
  int node = blockIdx.x*32 + (threadIdx.x >> 3);
  if (node >= n) return;
  int j = threadIdx.x & 7;
  int beg = rowptr[node], end = rowptr[node+1];
  float ard = ar[node];
  float mx = -1e30f;
  for (int e = beg; e < end; ++e){
    float v = al[csr_src[e]] + ard;
    v = v > 0.f ? v : SLOPE*v;
    mx = fmaxf(mx, v);
  }
  float acc = 0.f, den = 0.f;
  for (int e = beg; e < end; ++e){
    int s = csr_src[e];
    float v = al[s] + ard;
    v = v > 0.f ? v : SLOPE*v;
    float ex = expf(v - mx);
    den += ex;
    acc += ex * h2[(size_t)s*C2N + j];
  }
  float o = acc / (den + 1e-16f) + b2[j];
  int g = batch[node];
  atomicAdd(&pooled[g*C2N + j], o);
  if (j == 0) atomicAdd(&cnt[g], 1.f);
}

// ---- mean + log_softmax ----
__global__ __launch_bounds__(256) void k_final(const float* __restrict__ pooled,
    const float* __restrict__ cnt, float* __restrict__ out, int G){
  int g = blockIdx.x*blockDim.x + threadIdx.x;
  if (g >= G) return;
  float c = cnt[g]; c = c > 1.f ? c : 1.f;
  float p[8]; float mx = -1e30f;
  #pragma unroll
  for (int j = 0; j < 8; ++j){ p[j] = pooled[g*8+j] / c; mx = fmaxf(mx, p[j]); }
  float s = 0.f;
  #pragma unroll
  for (int j = 0; j < 8; ++j) s += expf(p[j]-mx);
  float lse = mx + logf(s);
  #pragma unroll
  for (int j = 0; j < 8; ++j) out[g*8+j] = p[j] - lse;
}

extern "C" void kernel_launch(void* const* d_in, const int* in_sizes, int n_in,
                              void* d_out, int out_size, void* d_ws, size_t ws_size,
                              hipStream_t stream){
  const float* x    = (const float*)d_in[0];
  const float* gam  = (const float*)d_in[1];
  const float* bet  = (const float*)d_in[2];
  const float* W1   = (const float*)d_in[3];
  const float* as1  = (const float*)d_in[4];
  const float* ad1  = (const float*)d_in[5];
  const float* b1   = (const float*)d_in[6];
  const float* W2   = (const float*)d_in[7];
  const float* as2  = (const float*)d_in[8];
  const float* ad2  = (const float*)d_in[9];
  const float* b2   = (const float*)d_in[10];
  const int*   ei   = (const int*)d_in[11];
  const int*   batch= (const int*)d_in[12];

  int N = in_sizes[0] / F1;
  int E = in_sizes[11] / 2;
  int G = out_size / C2N;
  int Etot = E + N;

  float* ws = (float*)d_ws;
  // ---- zero-init region ----
  float* sum    = ws;                         // 128
  float* sumsq  = sum + 128;                  // 128
  int*   deg    = (int*)(sumsq + 128);        // N
  float* pooled = (float*)(deg + N);          // G*8
  float* cnt    = pooled + (size_t)G*C2N;     // G
  float* zend   = cnt + G;
  size_t zero_bytes = (size_t)((char*)zend - (char*)ws);
  // ---- non-zeroed region ----
  float* ab      = zend;                      // 256
  int*   rowptr  = (int*)(ab + 256);          // N+1
  int*   cursor  = rowptr + N + 1;            // N
  int*   csr_src = cursor + N;                // Etot
  float* h1      = (float*)(csr_src + Etot);  // N*128
  float* x1      = h1 + (size_t)N*F1;         // N*128
  float* al1     = x1 + (size_t)N*F1;         // N*4
  float* ar1     = al1 + (size_t)N*4;         // N*4
  float* h2      = ar1 + (size_t)N*4;         // N*8
  float* al2     = h2 + (size_t)N*C2N;        // N
  float* ar2     = al2 + N;                   // N

  hipMemsetAsync(d_ws, 0, zero_bytes, stream);

  k_bn_stats<<<512, 128, 0, stream>>>(x, sum, sumsq, N);
  k_bn_final<<<1, 128, 0, stream>>>(sum, sumsq, gam, bet, ab, N);
  k_deg<<<(Etot + 255)/256, 256, 0, stream>>>(ei, deg, E, Etot);
  k_scan<<<1, 1024, 0, stream>>>(deg, rowptr, cursor, N, Etot);
  k_fill<<<(Etot + 255)/256, 256, 0, stream>>>(ei, cursor, csr_src, E, Etot);
  k_gemm1<<<(N + 7)/8, 128, 0, stream>>>(x, ab, W1, as1, ad1, h1, al1, ar1, N);
  k_gat1<<<(N + 3)/4, 256, 0, stream>>>(rowptr, csr_src, al1, ar1, h1, b1, x1, N);
  k_gemm2<<<(N + 31)/32, 256, 0, stream>>>(x1, W2, as2, ad2, h2, al2, ar2, N);
  k_gat2<<<(N + 31)/32, 256, 0, stream>>>(rowptr, csr_src, al2, ar2, h2, b2, batch, pooled, cnt, N);
  k_final<<<(G + 255)/256, 256, 0, stream>>>(pooled, cnt, (float*)d_out, G);
}

// Round 3
// 464.407 us; speedup vs baseline: 1.9411x; 1.1105x over previous
//
#include <hip/hip_runtime.h>
#include <hip/hip_fp16.h>
#include <math.h>

#define F1 128
#define C2N 8
#define SLOPE 0.2f
#define EPSBN 1e-5f

// ---- BatchNorm stats: thread = feature, block strides rows ----
__global__ __launch_bounds__(128) void k_bn_stats(const float* __restrict__ x,
    float* __restrict__ sum, float* __restrict__ sumsq, int n){
  int f = threadIdx.x;
  float s = 0.f, ss = 0.f;
  for (int r = blockIdx.x; r < n; r += gridDim.x){
    float v = x[(size_t)r*F1 + f];
    s += v; ss += v*v;
  }
  atomicAdd(&sum[f], s);
  atomicAdd(&sumsq[f], ss);
}

__global__ __launch_bounds__(128) void k_bn_final(const float* __restrict__ sum,
    const float* __restrict__ sumsq, const float* __restrict__ gamma,
    const float* __restrict__ beta, float* __restrict__ ab, int n){
  int f = threadIdx.x;
  float inv_n = 1.f / (float)n;
  float mean = sum[f] * inv_n;
  float var  = sumsq[f] * inv_n - mean*mean;
  float inv  = rsqrtf(var + EPSBN);
  float a = inv * gamma[f];
  ab[f]      = a;
  ab[F1 + f] = beta[f] - mean*a;
}

// ---- normalize + x@W1 (128x128) + al1/ar1; h1 stored fp16 ----
__global__ __launch_bounds__(128) void k_gemm1(const float* __restrict__ x,
    const float* __restrict__ ab, const float* __restrict__ W1,
    const float* __restrict__ asrc, const float* __restrict__ adst,
    __half* __restrict__ h1, float* __restrict__ al, float* __restrict__ ar, int n){
  const int j  = threadIdx.x;
  const int r0 = blockIdx.x * 8;
  __shared__ float xs[8][F1];
  float A = ab[j], B = ab[F1 + j];
  int nr = n - r0; if (nr > 8) nr = 8;
  for (int rr = 0; rr < nr; ++rr)
    xs[rr][j] = x[(size_t)(r0+rr)*F1 + j] * A + B;
  __syncthreads();
  float acc[8] = {0,0,0,0,0,0,0,0};
  for (int k = 0; k < F1; ++k){
    float w = W1[k*F1 + j];
    #pragma unroll
    for (int rr = 0; rr < 8; ++rr) acc[rr] += xs[rr][k] * w;
  }
  float as = asrc[j], ad = adst[j];
  for (int rr = 0; rr < nr; ++rr){
    float hv = acc[rr];
    h1[(size_t)(r0+rr)*F1 + j] = __float2half(hv);
    float vs = hv*as, vd = hv*ad;
    #pragma unroll
    for (int mk = 1; mk < 32; mk <<= 1){
      vs += __shfl_xor(vs, mk);
      vd += __shfl_xor(vd, mk);
    }
    if ((j & 31) == 0){
      al[(r0+rr)*4 + (j>>5)] = vs;
      ar[(r0+rr)*4 + (j>>5)] = vd;
    }
  }
}

// ---- CSR build: dst-degree histogram ----
__global__ __launch_bounds__(256) void k_deg(const int* __restrict__ ei,
    int* __restrict__ deg, int E, int Etot){
  int e = blockIdx.x*blockDim.x + threadIdx.x;
  if (e >= Etot) return;
  int d = (e < E) ? ei[E + e] : (e - E);
  atomicAdd(&deg[d], 1);
}

// ---- exclusive scan over N degrees (single block) ----
__global__ __launch_bounds__(1024) void k_scan(const int* __restrict__ deg,
    int* __restrict__ rowptr, int* __restrict__ cursor, int n, int Etot){
  __shared__ int ls[1024];
  int t = threadIdx.x;
  int C = (n + 1023) / 1024;
  int b = t*C, e = b+C; if (e > n) e = n;
  int s = 0;
  for (int i = b; i < e; ++i) s += deg[i];
  ls[t] = s; __syncthreads();
  for (int off = 1; off < 1024; off <<= 1){
    int v = (t >= off) ? ls[t-off] : 0;
    __syncthreads();
    ls[t] += v;
    __syncthreads();
  }
  int run = (t == 0) ? 0 : ls[t-1];
  for (int i = b; i < e; ++i){
    rowptr[i] = run; cursor[i] = run; run += deg[i];
  }
  if (t == 1023) rowptr[n] = Etot;
}

// ---- CSR fill: scatter src into dst-sorted order ----
__global__ __launch_bounds__(256) void k_fill(const int* __restrict__ ei,
    int* __restrict__ cursor, int* __restrict__ csr_src, int E, int Etot){
  int e = blockIdx.x*blockDim.x + threadIdx.x;
  if (e >= Etot) return;
  int s = (e < E) ? ei[e]     : (e - E);
  int d = (e < E) ? ei[E + e] : (e - E);
  int pos = atomicAdd(&cursor[d], 1);
  csr_src[pos] = s;
}

// ---- layer-1 GAT gather: 1 wave/node, 2 feats/lane, online softmax ----
__global__ __launch_bounds__(256) void k_gat1(const int* __restrict__ rowptr,
    const int* __restrict__ csr_src, const float* __restrict__ al,
    const float* __restrict__ ar, const __half* __restrict__ h1,
    const float* __restrict__ b1, float* __restrict__ x1, int n){
  int node = blockIdx.x*4 + (threadIdx.x >> 6);
  if (node >= n) return;
  int lane = threadIdx.x & 63;
  int f0 = lane*2;
  int h  = lane >> 4;
  int beg = rowptr[node], end = rowptr[node+1];
  float ard = ar[node*4 + h];
  float m = -1e30f, den = 0.f, a0 = 0.f, a1 = 0.f;
  for (int e = beg; e < end; ++e){
    int s = csr_src[e];
    float v = al[s*4 + h] + ard;
    v = v > 0.f ? v : SLOPE*v;
    float2 hv = __half22float2(*(const __half2*)&h1[(size_t)s*F1 + f0]);
    if (v > m){
      float sc = __expf(m - v);
      den = den*sc + 1.f;
      a0  = a0*sc + hv.x;
      a1  = a1*sc + hv.y;
      m = v;
    } else {
      float ex = __expf(v - m);
      den += ex;
      a0  += ex*hv.x;
      a1  += ex*hv.y;
    }
  }
  float inv = 1.f / (den + 1e-16f);
  float v0 = a0*inv + b1[f0];
  float v1 = a1*inv + b1[f0+1];
  x1[(size_t)node*F1 + f0]   = v0 > 0.f ? v0 : expm1f(v0);
  x1[(size_t)node*F1 + f0+1] = v1 > 0.f ? v1 : expm1f(v1);
}

// ---- x1@W2 (128x8) + al2/ar2 ----
__global__ __launch_bounds__(256) void k_gemm2(const float* __restrict__ x1,
    const float* __restrict__ W2, const float* __restrict__ as2,
    const float* __restrict__ ad2, float* __restrict__ h2,
    float* __restrict__ al2, float* __restrict__ ar2, int n){
  int r = blockIdx.x*32 + (threadIdx.x >> 3);
  int j = threadIdx.x & 7;
  if (r >= n) return;
  const float* xr = x1 + (size_t)r*F1;
  float a = 0.f;
  for (int k = 0; k < F1; ++k) a += xr[k] * W2[k*C2N + j];
  h2[(size_t)r*C2N + j] = a;
  float vs = a*as2[j], vd = a*ad2[j];
  #pragma unroll
  for (int mk = 1; mk < 8; mk <<= 1){
    vs += __shfl_xor(vs, mk);
    vd += __shfl_xor(vd, mk);
  }
  if (j == 0){ al2[r] = vs; ar2[r] = vd; }
}

// ---- layer-2 GAT gather + bias + pool scatter: 8 lanes/node, online ----
__global__ __launch_bounds__(256) void k_gat2(const int* __restrict__ rowptr,
    const int* __restrict__ csr_src, const float* __restrict__ al,
    const float* __restrict__ ar, const float* __restrict__ h2,
    const float* __restrict__ b2, const int* __restrict__ batch,
    float* __restrict__ pooled, float* __restrict__ cnt, int n){
  int node = blockIdx.x*32 + (threadIdx.x >> 3);
  if (node >= n) return;
  int j = threadIdx.x & 7;
  int beg = rowptr[node], end = rowptr[node+1];
  float ard = ar[node];
  float m = -1e30f, den = 0.f, acc = 0.f;
  for (int e = beg; e < end; ++e){
    int s = csr_src[e];
    float v = al[s] + ard;
    v = v > 0.f ? v : SLOPE*v;
    float hv = h2[(size_t)s*C2N + j];
    if (v > m){
      float sc = __expf(m - v);
      den = den*sc + 1.f;
      acc = acc*sc + hv;
      m = v;
    } else {
      float ex = __expf(v - m);
      den += ex;
      acc += ex*hv;
    }
  }
  float o = acc / (den + 1e-16f) + b2[j];
  int g = batch[node];
  atomicAdd(&pooled[g*C2N + j], o);
  if (j == 0) atomicAdd(&cnt[g], 1.f);
}

// ---- mean + log_softmax ----
__global__ __launch_bounds__(256) void k_final(const float* __restrict__ pooled,
    const float* __restrict__ cnt, float* __restrict__ out, int G){
  int g = blockIdx.x*blockDim.x + threadIdx.x;
  if (g >= G) return;
  float c = cnt[g]; c = c > 1.f ? c : 1.f;
  float p[8]; float mx = -1e30f;
  #pragma unroll
  for (int j = 0; j < 8; ++j){ p[j] = pooled[g*8+j] / c; mx = fmaxf(mx, p[j]); }
  float s = 0.f;
  #pragma unroll
  for (int j = 0; j < 8; ++j) s += expf(p[j]-mx);
  float lse = mx + logf(s);
  #pragma unroll
  for (int j = 0; j < 8; ++j) out[g*8+j] = p[j] - lse;
}

extern "C" void kernel_launch(void* const* d_in, const int* in_sizes, int n_in,
                              void* d_out, int out_size, void* d_ws, size_t ws_size,
                              hipStream_t stream){
  const float* x    = (const float*)d_in[0];
  const float* gam  = (const float*)d_in[1];
  const float* bet  = (const float*)d_in[2];
  const float* W1   = (const float*)d_in[3];
  const float* as1  = (const float*)d_in[4];
  const float* ad1  = (const float*)d_in[5];
  const float* b1   = (const float*)d_in[6];
  const float* W2   = (const float*)d_in[7];
  const float* as2  = (const float*)d_in[8];
  const float* ad2  = (const float*)d_in[9];
  const float* b2   = (const float*)d_in[10];
  const int*   ei   = (const int*)d_in[11];
  const int*   batch= (const int*)d_in[12];

  int N = in_sizes[0] / F1;
  int E = in_sizes[11] / 2;
  int G = out_size / C2N;
  int Etot = E + N;

  float* ws = (float*)d_ws;
  // ---- zero-init region ----
  float* sum    = ws;                         // 128
  float* sumsq  = sum + 128;                  // 128
  int*   deg    = (int*)(sumsq + 128);        // N
  float* pooled = (float*)(deg + N);          // G*8
  float* cnt    = pooled + (size_t)G*C2N;     // G
  float* zend   = cnt + G;
  size_t zero_bytes = (size_t)((char*)zend - (char*)ws);
  // ---- non-zeroed region ----
  float*  ab      = zend;                      // 256
  int*    rowptr  = (int*)(ab + 256);          // N+1
  int*    cursor  = rowptr + N + 1;            // N
  int*    csr_src = cursor + N;                // Etot
  __half* h1      = (__half*)(csr_src + Etot); // N*128 fp16
  float*  x1      = (float*)(h1 + (size_t)N*F1); // N*128 f32
  float*  al1     = x1 + (size_t)N*F1;         // N*4
  float*  ar1     = al1 + (size_t)N*4;         // N*4
  float*  h2      = ar1 + (size_t)N*4;         // N*8
  float*  al2     = h2 + (size_t)N*C2N;        // N
  float*  ar2     = al2 + N;                   // N

  hipMemsetAsync(d_ws, 0, zero_bytes, stream);

  k_bn_stats<<<512, 128, 0, stream>>>(x, sum, sumsq, N);
  k_bn_final<<<1, 128, 0, stream>>>(sum, sumsq, gam, bet, ab, N);
  k_deg<<<(Etot + 255)/256, 256, 0, stream>>>(ei, deg, E, Etot);
  k_scan<<<1, 1024, 0, stream>>>(deg, rowptr, cursor, N, Etot);
  k_fill<<<(Etot + 255)/256, 256, 0, stream>>>(ei, cursor, csr_src, E, Etot);
  k_gemm1<<<(N + 7)/8, 128, 0, stream>>>(x, ab, W1, as1, ad1, h1, al1, ar1, N);
  k_gat1<<<(N + 3)/4, 256, 0, stream>>>(rowptr, csr_src, al1, ar1, h1, b1, x1, N);
  k_gemm2<<<(N + 31)/32, 256, 0, stream>>>(x1, W2, as2, ad2, h2, al2, ar2, N);
  k_gat2<<<(N + 31)/32, 256, 0, stream>>>(rowptr, csr_src, al2, ar2, h2, b2, batch, pooled, cnt, N);
  k_final<<<(G + 255)/256, 256, 0, stream>>>(pooled, cnt, (float*)d_out, G);
}

// Round 4
// 362.662 us; speedup vs baseline: 2.4857x; 1.2806x over previous
//
#include <hip/hip_runtime.h>
#include <hip/hip_fp16.h>
#include <math.h>

#define F1 128
#define C2N 8
#define SLOPE 0.2f
#define EPSBN 1e-5f

// ---- BatchNorm stats: thread = feature, block strides rows ----
__global__ __launch_bounds__(128) void k_bn_stats(const float* __restrict__ x,
    float* __restrict__ sum, float* __restrict__ sumsq, int n){
  int f = threadIdx.x;
  float s = 0.f, ss = 0.f;
  for (int r = blockIdx.x; r < n; r += gridDim.x){
    float v = x[(size_t)r*F1 + f];
    s += v; ss += v*v;
  }
  atomicAdd(&sum[f], s);
  atomicAdd(&sumsq[f], ss);
}

__global__ __launch_bounds__(128) void k_bn_final(const float* __restrict__ sum,
    const float* __restrict__ sumsq, const float* __restrict__ gamma,
    const float* __restrict__ beta, float* __restrict__ ab, int n){
  int f = threadIdx.x;
  float inv_n = 1.f / (float)n;
  float mean = sum[f] * inv_n;
  float var  = sumsq[f] * inv_n - mean*mean;
  float inv  = rsqrtf(var + EPSBN);
  float a = inv * gamma[f];
  ab[f]      = a;
  ab[F1 + f] = beta[f] - mean*a;
}

// ---- normalize + x@W1 (128x128) + al1/ar1; h1 stored fp16 ----
__global__ __launch_bounds__(128) void k_gemm1(const float* __restrict__ x,
    const float* __restrict__ ab, const float* __restrict__ W1,
    const float* __restrict__ asrc, const float* __restrict__ adst,
    __half* __restrict__ h1, float* __restrict__ al, float* __restrict__ ar, int n){
  const int j  = threadIdx.x;
  const int r0 = blockIdx.x * 8;
  __shared__ float xs[8][F1];
  float A = ab[j], B = ab[F1 + j];
  int nr = n - r0; if (nr > 8) nr = 8;
  for (int rr = 0; rr < nr; ++rr)
    xs[rr][j] = x[(size_t)(r0+rr)*F1 + j] * A + B;
  __syncthreads();
  float acc[8] = {0,0,0,0,0,0,0,0};
  for (int k = 0; k < F1; ++k){
    float w = W1[k*F1 + j];
    #pragma unroll
    for (int rr = 0; rr < 8; ++rr) acc[rr] += xs[rr][k] * w;
  }
  float as = asrc[j], ad = adst[j];
  for (int rr = 0; rr < nr; ++rr){
    float hv = acc[rr];
    h1[(size_t)(r0+rr)*F1 + j] = __float2half(hv);
    float vs = hv*as, vd = hv*ad;
    #pragma unroll
    for (int mk = 1; mk < 32; mk <<= 1){
      vs += __shfl_xor(vs, mk);
      vd += __shfl_xor(vd, mk);
    }
    if ((j & 31) == 0){
      al[(r0+rr)*4 + (j>>5)] = vs;
      ar[(r0+rr)*4 + (j>>5)] = vd;
    }
  }
}

// ---- CSR build: dst-degree histogram ----
__global__ __launch_bounds__(256) void k_deg(const int* __restrict__ ei,
    int* __restrict__ deg, int E, int Etot){
  int e = blockIdx.x*blockDim.x + threadIdx.x;
  if (e >= Etot) return;
  int d = (e < E) ? ei[E + e] : (e - E);
  atomicAdd(&deg[d], 1);
}

// ---- scan stage A: per-block (1024 elems) local exclusive scan + block sum ----
__global__ __launch_bounds__(256) void k_scan_a(const int* __restrict__ deg,
    int* __restrict__ rowptr, int* __restrict__ bsum, int n){
  int t = threadIdx.x;
  int base = blockIdx.x*1024 + t*4;
  int4 v = {0,0,0,0};
  if (base + 3 < n) v = *(const int4*)&deg[base];
  else {
    if (base   < n) v.x = deg[base];
    if (base+1 < n) v.y = deg[base+1];
    if (base+2 < n) v.z = deg[base+2];
    if (base+3 < n) v.w = deg[base+3];
  }
  int s = v.x + v.y + v.z + v.w;
  __shared__ int ls[256];
  ls[t] = s; __syncthreads();
  for (int off = 1; off < 256; off <<= 1){
    int u = (t >= off) ? ls[t-off] : 0;
    __syncthreads();
    ls[t] += u;
    __syncthreads();
  }
  int ex = ls[t] - s;
  if (t == 255) bsum[blockIdx.x] = ls[255];
  int4 w;
  w.x = ex;
  w.y = ex + v.x;
  w.z = w.y + v.y;
  w.w = w.z + v.z;
  if (base + 3 < n) *(int4*)&rowptr[base] = w;
  else {
    if (base   < n) rowptr[base]   = w.x;
    if (base+1 < n) rowptr[base+1] = w.y;
    if (base+2 < n) rowptr[base+2] = w.z;
    if (base+3 < n) rowptr[base+3] = w.w;
  }
}

// ---- scan stage C: add block offsets, mirror into cursor ----
__global__ __launch_bounds__(256) void k_scan_c(int* __restrict__ rowptr,
    int* __restrict__ cursor, const int* __restrict__ bsum,
    int n, int Etot, int nb){
  int t = threadIdx.x;
  __shared__ int s_boff;
  if (t < 64){
    int b = blockIdx.x;
    int val = 0;
    for (int i = t; i < b; i += 64) val += bsum[i];
    #pragma unroll
    for (int m = 1; m < 64; m <<= 1) val += __shfl_xor(val, m);
    if (t == 0) s_boff = val;
  }
  __syncthreads();
  int boff = s_boff;
  int base = blockIdx.x*1024 + t*4;
  if (base + 3 < n){
    int4 v = *(int4*)&rowptr[base];
    v.x += boff; v.y += boff; v.z += boff; v.w += boff;
    *(int4*)&rowptr[base] = v;
    *(int4*)&cursor[base] = v;
  } else {
    for (int k = 0; k < 4; ++k)
      if (base + k < n){
        int v = rowptr[base+k] + boff;
        rowptr[base+k] = v; cursor[base+k] = v;
      }
  }
  if (blockIdx.x == 0 && t == 0) rowptr[n] = Etot;
}

// ---- CSR fill: scatter src into dst-sorted order ----
__global__ __launch_bounds__(256) void k_fill(const int* __restrict__ ei,
    int* __restrict__ cursor, int* __restrict__ csr_src, int E, int Etot){
  int e = blockIdx.x*blockDim.x + threadIdx.x;
  if (e >= Etot) return;
  int s = (e < E) ? ei[e]     : (e - E);
  int d = (e < E) ? ei[E + e] : (e - E);
  int pos = atomicAdd(&cursor[d], 1);
  csr_src[pos] = s;
}

// ---- layer-1 GAT gather: 1 wave/node, 2 feats/lane, online softmax ----
__global__ __launch_bounds__(256) void k_gat1(const int* __restrict__ rowptr,
    const int* __restrict__ csr_src, const float* __restrict__ al,
    const float* __restrict__ ar, const __half* __restrict__ h1,
    const float* __restrict__ b1, float* __restrict__ x1, int n){
  int node = blockIdx.x*4 + (threadIdx.x >> 6);
  if (node >= n) return;
  int lane = threadIdx.x & 63;
  int f0 = lane*2;
  int h  = lane >> 4;
  int beg = rowptr[node], end = rowptr[node+1];
  float ard = ar[node*4 + h];
  float m = -1e30f, den = 0.f, a0 = 0.f, a1 = 0.f;
  for (int e = beg; e < end; ++e){
    int s = csr_src[e];
    float v = al[s*4 + h] + ard;
    v = v > 0.f ? v : SLOPE*v;
    float2 hv = __half22float2(*(const __half2*)&h1[(size_t)s*F1 + f0]);
    if (v > m){
      float sc = __expf(m - v);
      den = den*sc + 1.f;
      a0  = a0*sc + hv.x;
      a1  = a1*sc + hv.y;
      m = v;
    } else {
      float ex = __expf(v - m);
      den += ex;
      a0  += ex*hv.x;
      a1  += ex*hv.y;
    }
  }
  float inv = 1.f / (den + 1e-16f);
  float v0 = a0*inv + b1[f0];
  float v1 = a1*inv + b1[f0+1];
  x1[(size_t)node*F1 + f0]   = v0 > 0.f ? v0 : expm1f(v0);
  x1[(size_t)node*F1 + f0+1] = v1 > 0.f ? v1 : expm1f(v1);
}

// ---- x1@W2 (128x8) + al2/ar2 ----
__global__ __launch_bounds__(256) void k_gemm2(const float* __restrict__ x1,
    const float* __restrict__ W2, const float* __restrict__ as2,
    const float* __restrict__ ad2, float* __restrict__ h2,
    float* __restrict__ al2, float* __restrict__ ar2, int n){
  int r = blockIdx.x*32 + (threadIdx.x >> 3);
  int j = threadIdx.x & 7;
  if (r >= n) return;
  const float* xr = x1 + (size_t)r*F1;
  float a = 0.f;
  for (int k = 0; k < F1; ++k) a += xr[k] * W2[k*C2N + j];
  h2[(size_t)r*C2N + j] = a;
  float vs = a*as2[j], vd = a*ad2[j];
  #pragma unroll
  for (int mk = 1; mk < 8; mk <<= 1){
    vs += __shfl_xor(vs, mk);
    vd += __shfl_xor(vd, mk);
  }
  if (j == 0){ al2[r] = vs; ar2[r] = vd; }
}

// ---- layer-2 GAT gather + bias + pool scatter: 8 lanes/node, online ----
__global__ __launch_bounds__(256) void k_gat2(const int* __restrict__ rowptr,
    const int* __restrict__ csr_src, const float* __restrict__ al,
    const float* __restrict__ ar, const float* __restrict__ h2,
    const float* __restrict__ b2, const int* __restrict__ batch,
    float* __restrict__ pooled, float* __restrict__ cnt, int n){
  int node = blockIdx.x*32 + (threadIdx.x >> 3);
  if (node >= n) return;
  int j = threadIdx.x & 7;
  int beg = rowptr[node], end = rowptr[node+1];
  float ard = ar[node];
  float m = -1e30f, den = 0.f, acc = 0.f;
  for (int e = beg; e < end; ++e){
    int s = csr_src[e];
    float v = al[s] + ard;
    v = v > 0.f ? v : SLOPE*v;
    float hv = h2[(size_t)s*C2N + j];
    if (v > m){
      float sc = __expf(m - v);
      den = den*sc + 1.f;
      acc = acc*sc + hv;
      m = v;
    } else {
      float ex = __expf(v - m);
      den += ex;
      acc += ex*hv;
    }
  }
  float o = acc / (den + 1e-16f) + b2[j];
  int g = batch[node];
  atomicAdd(&pooled[g*C2N + j], o);
  if (j == 0) atomicAdd(&cnt[g], 1.f);
}

// ---- mean + log_softmax ----
__global__ __launch_bounds__(256) void k_final(const float* __restrict__ pooled,
    const float* __restrict__ cnt, float* __restrict__ out, int G){
  int g = blockIdx.x*blockDim.x + threadIdx.x;
  if (g >= G) return;
  float c = cnt[g]; c = c > 1.f ? c : 1.f;
  float p[8]; float mx = -1e30f;
  #pragma unroll
  for (int j = 0; j < 8; ++j){ p[j] = pooled[g*8+j] / c; mx = fmaxf(mx, p[j]); }
  float s = 0.f;
  #pragma unroll
  for (int j = 0; j < 8; ++j) s += expf(p[j]-mx);
  float lse = mx + logf(s);
  #pragma unroll
  for (int j = 0; j < 8; ++j) out[g*8+j] = p[j] - lse;
}

extern "C" void kernel_launch(void* const* d_in, const int* in_sizes, int n_in,
                              void* d_out, int out_size, void* d_ws, size_t ws_size,
                              hipStream_t stream){
  const float* x    = (const float*)d_in[0];
  const float* gam  = (const float*)d_in[1];
  const float* bet  = (const float*)d_in[2];
  const float* W1   = (const float*)d_in[3];
  const float* as1  = (const float*)d_in[4];
  const float* ad1  = (const float*)d_in[5];
  const float* b1   = (const float*)d_in[6];
  const float* W2   = (const float*)d_in[7];
  const float* as2  = (const float*)d_in[8];
  const float* ad2  = (const float*)d_in[9];
  const float* b2   = (const float*)d_in[10];
  const int*   ei   = (const int*)d_in[11];
  const int*   batch= (const int*)d_in[12];

  int N = in_sizes[0] / F1;
  int E = in_sizes[11] / 2;
  int G = out_size / C2N;
  int Etot = E + N;
  int nb = (N + 1023) / 1024;

  float* ws = (float*)d_ws;
  // ---- zero-init region ----
  float* sum    = ws;                         // 128
  float* sumsq  = sum + 128;                  // 128
  int*   deg    = (int*)(sumsq + 128);        // N
  float* pooled = (float*)(deg + N);          // G*8
  float* cnt    = pooled + (size_t)G*C2N;     // G
  float* zend   = cnt + G;
  size_t zero_bytes = (size_t)((char*)zend - (char*)ws);
  // ---- non-zeroed region ----
  float*  ab      = zend;                      // 256
  int*    rowptr  = (int*)(ab + 256);          // N+1
  int*    cursor  = rowptr + N + 1;            // N
  int*    bsum    = cursor + N;                // nb
  int*    csr_src = bsum + nb;                 // Etot
  __half* h1      = (__half*)(csr_src + Etot); // N*128 fp16
  float*  x1      = (float*)(h1 + (size_t)N*F1); // N*128 f32
  float*  al1     = x1 + (size_t)N*F1;         // N*4
  float*  ar1     = al1 + (size_t)N*4;         // N*4
  float*  h2      = ar1 + (size_t)N*4;         // N*8
  float*  al2     = h2 + (size_t)N*C2N;        // N
  float*  ar2     = al2 + N;                   // N

  hipMemsetAsync(d_ws, 0, zero_bytes, stream);

  k_bn_stats<<<512, 128, 0, stream>>>(x, sum, sumsq, N);
  k_bn_final<<<1, 128, 0, stream>>>(sum, sumsq, gam, bet, ab, N);
  k_deg<<<(Etot + 255)/256, 256, 0, stream>>>(ei, deg, E, Etot);
  k_scan_a<<<nb, 256, 0, stream>>>(deg, rowptr, bsum, N);
  k_scan_c<<<nb, 256, 0, stream>>>(rowptr, cursor, bsum, N, Etot, nb);
  k_fill<<<(Etot + 255)/256, 256, 0, stream>>>(ei, cursor, csr_src, E, Etot);
  k_gemm1<<<(N + 7)/8, 128, 0, stream>>>(x, ab, W1, as1, ad1, h1, al1, ar1, N);
  k_gat1<<<(N + 3)/4, 256, 0, stream>>>(rowptr, csr_src, al1, ar1, h1, b1, x1, N);
  k_gemm2<<<(N + 31)/32, 256, 0, stream>>>(x1, W2, as2, ad2, h2, al2, ar2, N);
  k_gat2<<<(N + 31)/32, 256, 0, stream>>>(rowptr, csr_src, al2, ar2, h2, b2, batch, pooled, cnt, N);
  k_final<<<(G + 255)/256, 256, 0, stream>>>(pooled, cnt, (float*)d_out, G);
}

// Round 5
// 324.901 us; speedup vs baseline: 2.7746x; 1.1162x over previous
//
#include <hip/hip_runtime.h>
#include <hip/hip_fp16.h>
#include <math.h>

#define F1 128
#define C2N 8
#define SLOPE 0.2f
#define EPSBN 1e-5f

// ---- BatchNorm stats: thread = feature, block strides rows ----
__global__ __launch_bounds__(128) void k_bn_stats(const float* __restrict__ x,
    float* __restrict__ sum, float* __restrict__ sumsq, int n){
  int f = threadIdx.x;
  float s = 0.f, ss = 0.f;
  for (int r = blockIdx.x; r < n; r += gridDim.x){
    float v = x[(size_t)r*F1 + f];
    s += v; ss += v*v;
  }
  atomicAdd(&sum[f], s);
  atomicAdd(&sumsq[f], ss);
}

__global__ __launch_bounds__(128) void k_bn_final(const float* __restrict__ sum,
    const float* __restrict__ sumsq, const float* __restrict__ gamma,
    const float* __restrict__ beta, float* __restrict__ ab, int n){
  int f = threadIdx.x;
  float inv_n = 1.f / (float)n;
  float mean = sum[f] * inv_n;
  float var  = sumsq[f] * inv_n - mean*mean;
  float inv  = rsqrtf(var + EPSBN);
  float a = inv * gamma[f];
  ab[f]      = a;
  ab[F1 + f] = beta[f] - mean*a;
}

// ---- normalize + x@W1 (128x128) + al1/ar1; h1 stored fp16 ----
__global__ __launch_bounds__(128) void k_gemm1(const float* __restrict__ x,
    const float* __restrict__ ab, const float* __restrict__ W1,
    const float* __restrict__ asrc, const float* __restrict__ adst,
    __half* __restrict__ h1, float* __restrict__ al, float* __restrict__ ar, int n){
  const int j  = threadIdx.x;
  const int r0 = blockIdx.x * 8;
  __shared__ float xs[8][F1];
  float A = ab[j], B = ab[F1 + j];
  int nr = n - r0; if (nr > 8) nr = 8;
  for (int rr = 0; rr < nr; ++rr)
    xs[rr][j] = x[(size_t)(r0+rr)*F1 + j] * A + B;
  __syncthreads();
  float acc[8] = {0,0,0,0,0,0,0,0};
  for (int k = 0; k < F1; ++k){
    float w = W1[k*F1 + j];
    #pragma unroll
    for (int rr = 0; rr < 8; ++rr) acc[rr] += xs[rr][k] * w;
  }
  float as = asrc[j], ad = adst[j];
  for (int rr = 0; rr < nr; ++rr){
    float hv = acc[rr];
    h1[(size_t)(r0+rr)*F1 + j] = __float2half(hv);
    float vs = hv*as, vd = hv*ad;
    #pragma unroll
    for (int mk = 1; mk < 32; mk <<= 1){
      vs += __shfl_xor(vs, mk);
      vd += __shfl_xor(vd, mk);
    }
    if ((j & 31) == 0){
      al[(r0+rr)*4 + (j>>5)] = vs;
      ar[(r0+rr)*4 + (j>>5)] = vd;
    }
  }
}

// ---- CSR build: dst-degree histogram ----
__global__ __launch_bounds__(256) void k_deg(const int* __restrict__ ei,
    int* __restrict__ deg, int E, int Etot){
  int e = blockIdx.x*blockDim.x + threadIdx.x;
  if (e >= Etot) return;
  int d = (e < E) ? ei[E + e] : (e - E);
  atomicAdd(&deg[d], 1);
}

// ---- scan stage A: per-block (1024 elems) local exclusive scan + block sum ----
__global__ __launch_bounds__(256) void k_scan_a(const int* __restrict__ deg,
    int* __restrict__ rowptr, int* __restrict__ bsum, int n){
  int t = threadIdx.x;
  int base = blockIdx.x*1024 + t*4;
  int4 v = {0,0,0,0};
  if (base + 3 < n) v = *(const int4*)&deg[base];
  else {
    if (base   < n) v.x = deg[base];
    if (base+1 < n) v.y = deg[base+1];
    if (base+2 < n) v.z = deg[base+2];
    if (base+3 < n) v.w = deg[base+3];
  }
  int s = v.x + v.y + v.z + v.w;
  __shared__ int ls[256];
  ls[t] = s; __syncthreads();
  for (int off = 1; off < 256; off <<= 1){
    int u = (t >= off) ? ls[t-off] : 0;
    __syncthreads();
    ls[t] += u;
    __syncthreads();
  }
  int ex = ls[t] - s;
  if (t == 255) bsum[blockIdx.x] = ls[255];
  int4 w;
  w.x = ex;
  w.y = ex + v.x;
  w.z = w.y + v.y;
  w.w = w.z + v.z;
  if (base + 3 < n) *(int4*)&rowptr[base] = w;
  else {
    if (base   < n) rowptr[base]   = w.x;
    if (base+1 < n) rowptr[base+1] = w.y;
    if (base+2 < n) rowptr[base+2] = w.z;
    if (base+3 < n) rowptr[base+3] = w.w;
  }
}

// ---- scan stage C: add block offsets, mirror into cursor ----
__global__ __launch_bounds__(256) void k_scan_c(int* __restrict__ rowptr,
    int* __restrict__ cursor, const int* __restrict__ bsum,
    int n, int Etot, int nb){
  int t = threadIdx.x;
  __shared__ int s_boff;
  if (t < 64){
    int b = blockIdx.x;
    int val = 0;
    for (int i = t; i < b; i += 64) val += bsum[i];
    #pragma unroll
    for (int m = 1; m < 64; m <<= 1) val += __shfl_xor(val, m);
    if (t == 0) s_boff = val;
  }
  __syncthreads();
  int boff = s_boff;
  int base = blockIdx.x*1024 + t*4;
  if (base + 3 < n){
    int4 v = *(int4*)&rowptr[base];
    v.x += boff; v.y += boff; v.z += boff; v.w += boff;
    *(int4*)&rowptr[base] = v;
    *(int4*)&cursor[base] = v;
  } else {
    for (int k = 0; k < 4; ++k)
      if (base + k < n){
        int v = rowptr[base+k] + boff;
        rowptr[base+k] = v; cursor[base+k] = v;
      }
  }
  if (blockIdx.x == 0 && t == 0) rowptr[n] = Etot;
}

// ---- CSR fill: scatter src into dst-sorted order ----
__global__ __launch_bounds__(256) void k_fill(const int* __restrict__ ei,
    int* __restrict__ cursor, int* __restrict__ csr_src, int E, int Etot){
  int e = blockIdx.x*blockDim.x + threadIdx.x;
  if (e >= Etot) return;
  int s = (e < E) ? ei[e]     : (e - E);
  int d = (e < E) ? ei[E + e] : (e - E);
  int pos = atomicAdd(&cursor[d], 1);
  csr_src[pos] = s;
}

// ---- layer-1 GAT gather: 1 wave/node, chunk-parallel online softmax ----
// lane = (head h = lane>>4) x (edge slot sub = lane&15); features f0 = lane*2.
__global__ __launch_bounds__(256) void k_gat1(const int* __restrict__ rowptr,
    const int* __restrict__ csr_src, const float* __restrict__ al,
    const float* __restrict__ ar, const __half* __restrict__ h1,
    const float* __restrict__ b1, float* __restrict__ x1, int n){
  int node = blockIdx.x*4 + (threadIdx.x >> 6);
  if (node >= n) return;
  int lane = threadIdx.x & 63;
  int sub  = lane & 15;
  int h    = lane >> 4;
  int f0   = lane*2;
  int beg = rowptr[node], end = rowptr[node+1];
  float ard = ar[node*4 + h];
  float m = -1e30f, den = 0.f, a0 = 0.f, a1 = 0.f;

  int c = beg;
  // full 16-edge chunks
  for (; c + 16 <= end; c += 16){
    int s = csr_src[c + sub];
    float v = al[s*4 + h] + ard;
    v = v > 0.f ? v : SLOPE*v;
    float cm = v;
    cm = fmaxf(cm, __shfl_xor(cm, 1));
    cm = fmaxf(cm, __shfl_xor(cm, 2));
    cm = fmaxf(cm, __shfl_xor(cm, 4));
    cm = fmaxf(cm, __shfl_xor(cm, 8));
    float nm = fmaxf(m, cm);
    float sc = __expf(m - nm);
    float ex = __expf(v - nm);
    den = den*sc + ex;
    a0 *= sc; a1 *= sc; m = nm;
    #pragma unroll
    for (int k = 0; k < 16; ++k){
      int   sk  = __shfl(s, k);
      float exk = __shfl(ex, (h<<4) + k);
      float2 hv = __half22float2(*(const __half2*)&h1[((size_t)sk<<7) + f0]);
      a0 += exk*hv.x; a1 += exk*hv.y;
    }
  }
  // tail chunk
  if (c < end){
    int nv = end - c;
    bool valid = sub < nv;
    int s = valid ? csr_src[c + sub] : 0;
    float v = valid ? (al[s*4 + h] + ard) : -1e30f;
    v = v > 0.f ? v : SLOPE*v;
    float cm = v;
    cm = fmaxf(cm, __shfl_xor(cm, 1));
    cm = fmaxf(cm, __shfl_xor(cm, 2));
    cm = fmaxf(cm, __shfl_xor(cm, 4));
    cm = fmaxf(cm, __shfl_xor(cm, 8));
    float nm = fmaxf(m, cm);
    float sc = __expf(m - nm);
    float ex = __expf(v - nm);     // 0 for invalid lanes
    den = den*sc + ex;
    a0 *= sc; a1 *= sc; m = nm;
    #pragma unroll 4
    for (int k = 0; k < nv; ++k){
      int   sk  = __shfl(s, k);
      float exk = __shfl(ex, (h<<4) + k);
      float2 hv = __half22float2(*(const __half2*)&h1[((size_t)sk<<7) + f0]);
      a0 += exk*hv.x; a1 += exk*hv.y;
    }
  }
  // group-sum denominators (within 16-lane head group)
  den += __shfl_xor(den, 1);
  den += __shfl_xor(den, 2);
  den += __shfl_xor(den, 4);
  den += __shfl_xor(den, 8);

  float inv = 1.f / (den + 1e-16f);
  float v0 = a0*inv + b1[f0];
  float v1 = a1*inv + b1[f0+1];
  float2 o;
  o.x = v0 > 0.f ? v0 : expm1f(v0);
  o.y = v1 > 0.f ? v1 : expm1f(v1);
  *(float2*)&x1[((size_t)node<<7) + f0] = o;
}

// ---- x1@W2 (128x8) + al2/ar2 ----
__global__ __launch_bounds__(256) void k_gemm2(const float* __restrict__ x1,
    const float* __restrict__ W2, const float* __restrict__ as2,
    const float* __restrict__ ad2, float* __restrict__ h2,
    float* __restrict__ al2, float* __restrict__ ar2, int n){
  int r = blockIdx.x*32 + (threadIdx.x >> 3);
  int j = threadIdx.x & 7;
  if (r >= n) return;
  const float* xr = x1 + (size_t)r*F1;
  float a = 0.f;
  for (int k = 0; k < F1; ++k) a += xr[k] * W2[k*C2N + j];
  h2[(size_t)r*C2N + j] = a;
  float vs = a*as2[j], vd = a*ad2[j];
  #pragma unroll
  for (int mk = 1; mk < 8; mk <<= 1){
    vs += __shfl_xor(vs, mk);
    vd += __shfl_xor(vd, mk);
  }
  if (j == 0){ al2[r] = vs; ar2[r] = vd; }
}

// ---- layer-2 GAT gather + bias + pool scatter: 8 lanes/node, chunked ----
__global__ __launch_bounds__(256) void k_gat2(const int* __restrict__ rowptr,
    const int* __restrict__ csr_src, const float* __restrict__ al,
    const float* __restrict__ ar, const float* __restrict__ h2,
    const float* __restrict__ b2, const int* __restrict__ batch,
    float* __restrict__ pooled, float* __restrict__ cnt, int n){
  int node = blockIdx.x*32 + (threadIdx.x >> 3);
  if (node >= n) return;
  int lane = threadIdx.x & 63;
  int sub  = lane & 7;            // edge slot AND feature index
  int base = lane & ~7;           // group start lane (absolute in wave)
  int beg = rowptr[node], end = rowptr[node+1];
  float ard = ar[node];
  float m = -1e30f, den = 0.f, acc = 0.f;

  int c = beg;
  for (; c + 8 <= end; c += 8){
    int s = csr_src[c + sub];
    float v = al[s] + ard;
    v = v > 0.f ? v : SLOPE*v;
    float cm = v;
    cm = fmaxf(cm, __shfl_xor(cm, 1));
    cm = fmaxf(cm, __shfl_xor(cm, 2));
    cm = fmaxf(cm, __shfl_xor(cm, 4));
    float nm = fmaxf(m, cm);
    float sc = __expf(m - nm);
    float ex = __expf(v - nm);
    den = den*sc + ex;
    acc *= sc; m = nm;
    #pragma unroll
    for (int k = 0; k < 8; ++k){
      int   sk  = __shfl(s, base + k);
      float exk = __shfl(ex, base + k);
      acc += exk * h2[((size_t)sk<<3) + sub];
    }
  }
  if (c < end){
    int nv = end - c;
    bool valid = sub < nv;
    int s = valid ? csr_src[c + sub] : 0;
    float v = valid ? (al[s] + ard) : -1e30f;
    v = v > 0.f ? v : SLOPE*v;
    float cm = v;
    cm = fmaxf(cm, __shfl_xor(cm, 1));
    cm = fmaxf(cm, __shfl_xor(cm, 2));
    cm = fmaxf(cm, __shfl_xor(cm, 4));
    float nm = fmaxf(m, cm);
    float sc = __expf(m - nm);
    float ex = __expf(v - nm);
    den = den*sc + ex;
    acc *= sc; m = nm;
    #pragma unroll 4
    for (int k = 0; k < nv; ++k){
      int   sk  = __shfl(s, base + k);
      float exk = __shfl(ex, base + k);
      acc += exk * h2[((size_t)sk<<3) + sub];
    }
  }
  den += __shfl_xor(den, 1);
  den += __shfl_xor(den, 2);
  den += __shfl_xor(den, 4);

  float o = acc / (den + 1e-16f) + b2[sub];
  int g = batch[node];
  atomicAdd(&pooled[g*C2N + sub], o);
  if (sub == 0) atomicAdd(&cnt[g], 1.f);
}

// ---- mean + log_softmax ----
__global__ __launch_bounds__(256) void k_final(const float* __restrict__ pooled,
    const float* __restrict__ cnt, float* __restrict__ out, int G){
  int g = blockIdx.x*blockDim.x + threadIdx.x;
  if (g >= G) return;
  float c = cnt[g]; c = c > 1.f ? c : 1.f;
  float p[8]; float mx = -1e30f;
  #pragma unroll
  for (int j = 0; j < 8; ++j){ p[j] = pooled[g*8+j] / c; mx = fmaxf(mx, p[j]); }
  float s = 0.f;
  #pragma unroll
  for (int j = 0; j < 8; ++j) s += expf(p[j]-mx);
  float lse = mx + logf(s);
  #pragma unroll
  for (int j = 0; j < 8; ++j) out[g*8+j] = p[j] - lse;
}

extern "C" void kernel_launch(void* const* d_in, const int* in_sizes, int n_in,
                              void* d_out, int out_size, void* d_ws, size_t ws_size,
                              hipStream_t stream){
  const float* x    = (const float*)d_in[0];
  const float* gam  = (const float*)d_in[1];
  const float* bet  = (const float*)d_in[2];
  const float* W1   = (const float*)d_in[3];
  const float* as1  = (const float*)d_in[4];
  const float* ad1  = (const float*)d_in[5];
  const float* b1   = (const float*)d_in[6];
  const float* W2   = (const float*)d_in[7];
  const float* as2  = (const float*)d_in[8];
  const float* ad2  = (const float*)d_in[9];
  const float* b2   = (const float*)d_in[10];
  const int*   ei   = (const int*)d_in[11];
  const int*   batch= (const int*)d_in[12];

  int N = in_sizes[0] / F1;
  int E = in_sizes[11] / 2;
  int G = out_size / C2N;
  int Etot = E + N;
  int nb = (N + 1023) / 1024;

  float* ws = (float*)d_ws;
  // ---- zero-init region ----
  float* sum    = ws;                         // 128
  float* sumsq  = sum + 128;                  // 128
  int*   deg    = (int*)(sumsq + 128);        // N
  float* pooled = (float*)(deg + N);          // G*8
  float* cnt    = pooled + (size_t)G*C2N;     // G
  float* zend   = cnt + G;
  size_t zero_bytes = (size_t)((char*)zend - (char*)ws);
  // ---- non-zeroed region ----
  float*  ab      = zend;                      // 256
  int*    rowptr  = (int*)(ab + 256);          // N+1
  int*    cursor  = rowptr + N + 1;            // N
  int*    bsum    = cursor + N;                // nb
  int*    csr_src = bsum + nb;                 // Etot
  __half* h1      = (__half*)(csr_src + Etot); // N*128 fp16
  float*  x1      = (float*)(h1 + (size_t)N*F1); // N*128 f32
  float*  al1     = x1 + (size_t)N*F1;         // N*4
  float*  ar1     = al1 + (size_t)N*4;         // N*4
  float*  h2      = ar1 + (size_t)N*4;         // N*8
  float*  al2     = h2 + (size_t)N*C2N;        // N
  float*  ar2     = al2 + N;                   // N

  hipMemsetAsync(d_ws, 0, zero_bytes, stream);

  k_bn_stats<<<512, 128, 0, stream>>>(x, sum, sumsq, N);
  k_bn_final<<<1, 128, 0, stream>>>(sum, sumsq, gam, bet, ab, N);
  k_deg<<<(Etot + 255)/256, 256, 0, stream>>>(ei, deg, E, Etot);
  k_scan_a<<<nb, 256, 0, stream>>>(deg, rowptr, bsum, N);
  k_scan_c<<<nb, 256, 0, stream>>>(rowptr, cursor, bsum, N, Etot, nb);
  k_fill<<<(Etot + 255)/256, 256, 0, stream>>>(ei, cursor, csr_src, E, Etot);
  k_gemm1<<<(N + 7)/8, 128, 0, stream>>>(x, ab, W1, as1, ad1, h1, al1, ar1, N);
  k_gat1<<<(N + 3)/4, 256, 0, stream>>>(rowptr, csr_src, al1, ar1, h1, b1, x1, N);
  k_gemm2<<<(N + 31)/32, 256, 0, stream>>>(x1, W2, as2, ad2, h2, al2, ar2, N);
  k_gat2<<<(N + 31)/32, 256, 0, stream>>>(rowptr, csr_src, al2, ar2, h2, b2, batch, pooled, cnt, N);
  k_final<<<(G + 255)/256, 256, 0, stream>>>(pooled, cnt, (float*)d_out, G);
}